// Round 13
// baseline (211.414 us; speedup 1.0000x reference)
//
#include <hip/hip_runtime.h>
#include <math.h>

// Problem constants
#define B_  64
#define T_  256
#define IN_ 512
#define HID_ 1024
#define OUT_ 256
#define NDOM 20

typedef __bf16 bf16_t;
typedef __bf16 bf16x8 __attribute__((ext_vector_type(8)));
typedef float  f32x4  __attribute__((ext_vector_type(4)));

// fp32 -> bf16 RNE, pure bit math
__device__ __forceinline__ unsigned f2bf_bits(float f) {
    unsigned u = __builtin_bit_cast(unsigned, f);
    return (u + 0x7FFFu + ((u >> 16) & 1u)) >> 16;
}
__device__ __forceinline__ unsigned pack_bf16x2(float x, float y) {
    return f2bf_bits(x) | (f2bf_bits(y) << 16);
}

// Async global->LDS, 16 B per lane. LDS dest = wave-uniform base + lane*16 (m104).
__device__ __forceinline__ void gl_lds16(const void* g, void* l) {
    __builtin_amdgcn_global_load_lds(
        (const __attribute__((address_space(1))) unsigned*)g,
        (__attribute__((address_space(3))) unsigned*)l,
        16, 0, 0);
}

// ---------------------------------------------------------------------------
// Fused prepass (one dispatch, 12032 blocks) — unchanged from R11:
//   [0,8192): X fp32 -> Xbf bf16;  [8192,10752): W1 -> W1t + b1;
//   [10752,12032): W2 -> W2t + b2
__global__ __launch_bounds__(256) void prepass(
    const float* __restrict__ X,  bf16_t* __restrict__ Xbf,
    const float* __restrict__ t1, bf16_t* __restrict__ W1t, float* __restrict__ b1,
    const float* __restrict__ t2, bf16_t* __restrict__ W2t, float* __restrict__ b2)
{
    const int bid = blockIdx.x;
    const int tid = threadIdx.x;

    if (bid < 8192) {
        const size_t idx = (size_t)bid * 256 + tid;
        float4 v = ((const float4*)X)[idx];
        uint2 p;
        p.x = pack_bf16x2(v.x, v.y);
        p.y = pack_bf16x2(v.z, v.w);
        ((uint2*)Xbf)[idx] = p;
        return;
    }

    __shared__ float t[64][65];

    const float* table; bf16_t* Wt; float* Bias;
    int K, N, d, n0, k0;
    if (bid < 10752) {
        const int r = bid - 8192;
        K = IN_; N = HID_;
        d = r >> 7;
        n0 = (r & 15) * 64;
        k0 = ((r >> 4) & 7) * 64;
        table = t1; Wt = W1t; Bias = b1;
    } else {
        const int r = bid - 10752;
        K = HID_; N = OUT_;
        d = r >> 6;
        n0 = (r & 3) * 64;
        k0 = ((r >> 2) & 15) * 64;
        table = t2; Wt = W2t; Bias = b2;
    }

    const float* W = table + (size_t)d * ((size_t)K * N + N);

    #pragma unroll
    for (int r = 0; r < 4; ++r) {
        const int kl = (tid >> 4) + r * 16;
        const int nl = (tid & 15) * 4;
        float4 v = *(const float4*)(W + (size_t)(k0 + kl) * N + n0 + nl);
        t[kl][nl + 0] = v.x; t[kl][nl + 1] = v.y;
        t[kl][nl + 2] = v.z; t[kl][nl + 3] = v.w;
    }
    __syncthreads();

    bf16_t* Wtd = Wt + (size_t)d * K * N;
    #pragma unroll
    for (int r = 0; r < 4; ++r) {
        const int nl = (tid >> 4) + r * 16;
        const int k4 = (tid & 15) * 4;
        uint2 p;
        p.x = pack_bf16x2(t[k4 + 0][nl], t[k4 + 1][nl]);
        p.y = pack_bf16x2(t[k4 + 2][nl], t[k4 + 3][nl]);
        *(uint2*)(Wtd + (size_t)(n0 + nl) * K + k0 + k4) = p;
    }

    if (k0 == 0 && tid < 64)
        Bias[(size_t)d * N + n0 + tid] = W[(size_t)K * N + n0 + tid];
}

// ---------------------------------------------------------------------------
// fc1: H[b] = gelu(Xbf[b] @ W1t[d]^T + b1).  Block 64m x 256n, BK=64, 8 iters.
// R13: B-fragments loaded DIRECTLY global->VGPR (16 B contiguous per lane from
// [n][k] layout; L2-hot; no barrier dependency -> prefetchable). Only A (Xbf)
// goes through LDS, double-buffered, ONE barrier per iter. Wave tile 64m x 64n
// (B rows unique per wave; A shared by all 4 waves).
// Swapped-operand MFMA (D^T): m = lane&15, n = quad*4+reg  [R10-validated].
#define CT1_STRIDE 264   // 256 data + 8 pad bf16 = 528 B = 33*16 (16-B mult!)
__global__ __launch_bounds__(256) void fc1_gemm(
    const bf16_t* __restrict__ Xbf,   // B x 256 x 512
    const bf16_t* __restrict__ W1t,   // D x 1024 x 512 [n][k]
    const float*  __restrict__ Bias,  // D x 1024
    const int*    __restrict__ hetero,
    bf16_t*       __restrict__ H)     // B x 256 x 1024
{
    const int id   = blockIdx.x;          // 1024 blocks
    const int b    = id & 63;             // same-b at stride 64 -> same XCD (64%8==0)
    const int rest = id >> 6;             // 0..15
    const int m0   = (rest & 3) * 64;
    const int n0   = (rest >> 2) * 256;
    const int d    = hetero[2 * b];
    const bf16_t* W    = W1t + (size_t)d * HID_ * IN_;
    const float*  bias = Bias + (size_t)d * HID_;
    const bf16_t* A    = Xbf + (size_t)(b * 256 + m0) * IN_;

    __shared__ __attribute__((aligned(16))) char smem[64 * CT1_STRIDE * 2]; // 33792 B
    bf16_t* LdsA0 = (bf16_t*)smem;            // [64][64] 8 KB  (k-buffer 0)
    bf16_t* LdsA1 = (bf16_t*)(smem + 8192);   // [64][64] 8 KB  (k-buffer 1)
    bf16_t* Ct    = (bf16_t*)smem;            // epilogue [64][CT1_STRIDE] (aliases)

    const int tid  = threadIdx.x;
    const int wave = tid >> 6;
    const int lane = tid & 63;
    const int l16  = lane & 15;
    const int quad = lane >> 4;
    const int wn   = wave * 64;           // wave tile 64m x 64n

    // A staging: 64 rows x 128 B, 2 gl_lds16 calls/wave, XOR swizzle (row&7).
    const int st_r0a = wave * 16;
    const int st_row = lane >> 3;
    const int st_c   = lane & 7;

    f32x4 acc[4][4] = {};

    // Prologue: stage k-block 0 into buf0.
    {
        bf16_t* dst = LdsA0;
        #pragma unroll
        for (int cc = 0; cc < 2; ++cc) {
            const int r0  = st_r0a + cc * 8;
            const int row = r0 + st_row;
            const int cs  = st_c ^ (row & 7);
            gl_lds16(A + (size_t)row * IN_ + cs * 8, &dst[r0 * 64]);
        }
    }

    for (int kki = 0; kki < 8; ++kki) {
        const int kk = kki * 64;
        __syncthreads();   // buf[kki&1] ready (vmcnt drained by compiler)

        bf16_t* cur = (kki & 1) ? LdsA1 : LdsA0;
        if (kki < 7) {     // stage next k-block into other buffer (async)
            bf16_t* nxt = (kki & 1) ? LdsA0 : LdsA1;
            #pragma unroll
            for (int cc = 0; cc < 2; ++cc) {
                const int r0  = st_r0a + cc * 8;
                const int row = r0 + st_row;
                const int cs  = st_c ^ (row & 7);
                gl_lds16(A + (size_t)row * IN_ + kk + 64 + cs * 8, &nxt[r0 * 64]);
            }
        }

        // B fragments: 8 direct global loads (j=0..3, h=0..1), issued up front.
        bf16x8 bfg[2][4];
        #pragma unroll
        for (int h = 0; h < 2; ++h)
            #pragma unroll
            for (int j = 0; j < 4; ++j)
                bfg[h][j] = *(const bf16x8*)(W +
                    (size_t)(n0 + wn + j * 16 + l16) * IN_ + kk + h * 32 + quad * 8);

        #pragma unroll
        for (int h = 0; h < 2; ++h) {
            bf16x8 af[4];
            #pragma unroll
            for (int i = 0; i < 4; ++i) {
                const int r = i * 16 + l16;
                const int c = (h * 4 + quad) ^ (r & 7);
                af[i] = *(const bf16x8*)&cur[r * 64 + c * 8];
            }
            #pragma unroll
            for (int i = 0; i < 4; ++i)
                #pragma unroll
                for (int j = 0; j < 4; ++j)   // swapped operands -> D^T
                    acc[i][j] = __builtin_amdgcn_mfma_f32_16x16x32_bf16(bfg[h][j], af[i], acc[i][j], 0, 0, 0);
        }
    }
    __syncthreads();   // all compute done before Ct aliases the A buffers

    // Epilogue: m = i*16+l16, n = wn + j*16 + quad*4 + reg (4 consecutive).
    #pragma unroll
    for (int i = 0; i < 4; ++i) {
        const int m = i * 16 + l16;
        #pragma unroll
        for (int j = 0; j < 4; ++j) {
            const int nl = wn + j * 16 + quad * 4;
            const float4 b4 = *(const float4*)&bias[n0 + nl];
            float v0 = acc[i][j][0] + b4.x;
            float v1 = acc[i][j][1] + b4.y;
            float v2 = acc[i][j][2] + b4.z;
            float v3 = acc[i][j][3] + b4.w;
            v0 = 0.5f * v0 * (1.0f + erff(v0 * 0.70710678f));
            v1 = 0.5f * v1 * (1.0f + erff(v1 * 0.70710678f));
            v2 = 0.5f * v2 * (1.0f + erff(v2 * 0.70710678f));
            v3 = 0.5f * v3 * (1.0f + erff(v3 * 0.70710678f));
            uint2 p;
            p.x = pack_bf16x2(v0, v1);
            p.y = pack_bf16x2(v2, v3);
            *(uint2*)&Ct[m * CT1_STRIDE + nl] = p;
        }
    }
    __syncthreads();

    // Coalesced H store: 64 rows x 512 B (32 chunks of 16 B per row).
    #pragma unroll
    for (int it = 0; it < 8; ++it) {
        const int row = it * 8 + (tid >> 5);
        const int ch  = tid & 31;
        uint4 v = *(const uint4*)&Ct[row * CT1_STRIDE + ch * 8];
        *(uint4*)&H[((size_t)(b * 256 + m0 + row)) * HID_ + n0 + ch * 8] = v;
    }
}

// ---------------------------------------------------------------------------
// fc2: out[b] = H[b] @ W2t[d]^T + b2.  Block 32m x 256n (full OUT -> H read
// exactly once), BK=64, 16 iters. Same R13 structure: B (W2t) fragments direct
// global->VGPR; A (H) LDS double-buffered, one barrier/iter. Wave 32m x 64n.
__global__ __launch_bounds__(256) void fc2_gemm(
    const bf16_t* __restrict__ H,
    const bf16_t* __restrict__ W2t,   // D x 256 x 1024 [n][k]
    const float*  __restrict__ Bias,  // D x 256
    const int*    __restrict__ hetero,
    float*        __restrict__ Out)   // B x 256 x 256
{
    const int id   = blockIdx.x;          // 512 blocks
    const int b    = id & 63;             // same-b at stride 64 -> same XCD
    const int m0   = (id >> 6) * 32;      // 8 m-tiles of 32 rows
    const int d    = hetero[2 * b];
    const bf16_t* W    = W2t + (size_t)d * OUT_ * HID_;
    const float*  bias = Bias + (size_t)d * OUT_;
    const bf16_t* A    = H + (size_t)(b * 256 + m0) * HID_;

    __shared__ __attribute__((aligned(16))) bf16_t LdsA[2][32 * 64];  // 2 x 4 KB

    const int tid  = threadIdx.x;
    const int wave = tid >> 6;
    const int lane = tid & 63;
    const int l16  = lane & 15;
    const int quad = lane >> 4;
    const int wn   = wave * 64;

    // A staging: 32 rows x 128 B = 256 lane-loads, 1 call/thread.
    const int st_r0  = wave * 8;
    const int st_row = lane >> 3;
    const int st_c   = lane & 7;

    f32x4 acc[2][4] = {};

    {
        const int row = st_r0 + st_row;
        const int cs  = st_c ^ (row & 7);
        gl_lds16(A + (size_t)row * HID_ + cs * 8, &LdsA[0][st_r0 * 64]);
    }

    for (int kki = 0; kki < 16; ++kki) {
        const int kk = kki * 64;
        __syncthreads();

        const bf16_t* cur = LdsA[kki & 1];
        if (kki < 15) {
            bf16_t* nxt = LdsA[(kki + 1) & 1];
            const int row = st_r0 + st_row;
            const int cs  = st_c ^ (row & 7);
            gl_lds16(A + (size_t)row * HID_ + kk + 64 + cs * 8, &nxt[st_r0 * 64]);
        }

        bf16x8 bfg[2][4];
        #pragma unroll
        for (int h = 0; h < 2; ++h)
            #pragma unroll
            for (int j = 0; j < 4; ++j)
                bfg[h][j] = *(const bf16x8*)(W +
                    (size_t)(wn + j * 16 + l16) * HID_ + kk + h * 32 + quad * 8);

        #pragma unroll
        for (int h = 0; h < 2; ++h) {
            bf16x8 af[2];
            #pragma unroll
            for (int i = 0; i < 2; ++i) {
                const int r = i * 16 + l16;
                const int c = (h * 4 + quad) ^ (r & 7);
                af[i] = *(const bf16x8*)&cur[r * 64 + c * 8];
            }
            #pragma unroll
            for (int i = 0; i < 2; ++i)
                #pragma unroll
                for (int j = 0; j < 4; ++j)   // swapped operands -> D^T
                    acc[i][j] = __builtin_amdgcn_mfma_f32_16x16x32_bf16(bfg[h][j], af[i], acc[i][j], 0, 0, 0);
        }
    }

    // Store: m = m0 + i*16 + l16; n = wn + j*16 + quad*4 (+reg). dwordx4/lane.
    #pragma unroll
    for (int i = 0; i < 2; ++i) {
        const int m = m0 + i * 16 + l16;
        #pragma unroll
        for (int j = 0; j < 4; ++j) {
            const int nl = wn + j * 16 + quad * 4;
            const float4 b4 = *(const float4*)&bias[nl];
            float4 o;
            o.x = acc[i][j][0] + b4.x;
            o.y = acc[i][j][1] + b4.y;
            o.z = acc[i][j][2] + b4.z;
            o.w = acc[i][j][3] + b4.w;
            *(float4*)&Out[(size_t)(b * 256 + m) * OUT_ + nl] = o;
        }
    }
}

extern "C" void kernel_launch(void* const* d_in, const int* in_sizes, int n_in,
                              void* d_out, int out_size, void* d_ws, size_t ws_size,
                              hipStream_t stream) {
    const float* x         = (const float*)d_in[0];
    const int*   hetero    = (const int*)d_in[1];
    const float* fc1_table = (const float*)d_in[2];
    const float* fc2_table = (const float*)d_in[3];
    float*       out       = (float*)d_out;

    // Workspace layout (validated budget):
    char* ws = (char*)d_ws;
    bf16_t* W1t = (bf16_t*)(ws);                         // 20x1024x512 bf16
    bf16_t* W2t = (bf16_t*)(ws + 20971520);              // 20x256x1024 bf16
    float*  b1  = (float*)(ws + 31457280);               // 20x1024 fp32
    float*  b2  = (float*)(ws + 31539200);               // 20x256 fp32
    bf16_t* H   = (bf16_t*)(ws + 31559680);              // 64x256x1024 bf16

    // Xbf lives in d_out: fc1 reads it, fc2 overwrites later (stream-ordered).
    bf16_t* Xbf = (bf16_t*)d_out;

    prepass<<<dim3(12032), 256, 0, stream>>>(
        x, Xbf, fc1_table, W1t, b1, fc2_table, W2t, b2);

    fc1_gemm<<<dim3(1024), 256, 0, stream>>>(Xbf, W1t, b1, hetero, H);
    fc2_gemm<<<dim3(512), 256, 0, stream>>>(H, W2t, b2, hetero, out);
}